// Round 10
// baseline (1291.747 us; speedup 1.0000x reference)
//
#include <hip/hip_runtime.h>
#include <stdint.h>

#define B_ 256
#define T_ 512
#define F_ 128
#define U_ 256
#define H_ 64
#define G4U (4 * U_)

typedef __attribute__((ext_vector_type(8))) short short8;
typedef __attribute__((ext_vector_type(4))) float f32x4;
typedef unsigned long long ull;

// LDS-only barrier: NO vmcnt drain (publish/seq stores stay in flight).
#define BARRIER_LDS() asm volatile("s_waitcnt lgkmcnt(0)\ns_barrier" ::: "memory")

__device__ __forceinline__ uint16_t f2bf(float f) {
  uint32_t u = __builtin_bit_cast(uint32_t, f);
  u += 0x7fffu + ((u >> 16) & 1u);
  return (uint16_t)(u >> 16);
}
__device__ __forceinline__ float bf2f(uint32_t v) {
  return __builtin_bit_cast(float, (v & 0xffffu) << 16);
}
__device__ __forceinline__ float sigm(float z) {
  return 1.0f / (1.0f + __expf(-z));
}
__device__ __forceinline__ ull ald(const ull* p) {
  return __hip_atomic_load(p, __ATOMIC_RELAXED, __HIP_MEMORY_SCOPE_AGENT);
}

// ---------------------------------------------------------------------------
// Pre-kernel: xz[bgm][t] = bias + x_t @ kernel for member m's 512 gate-cols,
// stored bf16 in MFMA C-layout: [bgm(32)][t(512)][wv(8)][q(4)][lane(64)][j(4)].
// 256 WGs (bgm x 8 t-chunks) x 256 threads (wave = gate q). BW-bound ~75us.
// ---------------------------------------------------------------------------
__global__ __launch_bounds__(256, 1) void xz_pre_kernel(
    const float* __restrict__ x, const float* __restrict__ kern,
    const float* __restrict__ bias, uint16_t* __restrict__ xz)
{
  const int tid  = threadIdx.x;
  const int lane = tid & 63;
  const int q    = tid >> 6;          // wave = gate
  const int il   = lane & 15;
  const int bgm  = blockIdx.x & 31;   // bg*2 + m
  const int tc   = blockIdx.x >> 5;   // 0..7
  const int bg   = bgm >> 1, m = bgm & 1;

  __shared__ __align__(16) uint16_t kern_lds[8192 * 8];     // 128 KB
  __shared__ __align__(16) uint16_t x_stage[2][4][64][8];   // 8 KB dbuf

  // stage kern B-frags: slot = ((q*8+ct)*4+kt)*64+ln
  for (int s = 0; s < 32; ++s) {
    const int slot = tid + s * 256;
    const int ln = slot & 63, kt = (slot >> 6) & 3, ctq = slot >> 8;
    const int col = (ctq >> 3) * U_ + m * 128 + (ctq & 7) * 16 + (ln & 15);
    const int kb  = kt * 32 + (ln >> 4) * 8;
    short8 v;
    #pragma unroll
    for (int j = 0; j < 8; ++j)
      v[j] = (short)f2bf(kern[(size_t)(kb + j) * G4U + col]);
    *(short8*)&kern_lds[(size_t)slot * 8] = v;
  }
  float bias_r[8];
  #pragma unroll
  for (int ct = 0; ct < 8; ++ct)
    bias_r[ct] = bias[q * U_ + m * 128 + ct * 16 + il];

  const int xrow = tid & 15, xfb = (tid >> 4) * 8;
  const int xs_kt = xfb >> 5, xs_l = (((xfb & 31) >> 3) * 16) + xrow;

  float xv[8];
  {
    const float* p = x + ((size_t)(bg * 16 + xrow) * T_ + tc * 64) * F_ + xfb;
    #pragma unroll
    for (int j = 0; j < 8; ++j) xv[j] = p[j];
  }
  __syncthreads();   // kern_lds ready

  for (int tt = 0; tt < 64; ++tt) {
    const int t = tc * 64 + tt;
    const int bb = tt & 1;
    {
      uint16_t* d = &x_stage[bb][xs_kt][xs_l][0];
      #pragma unroll
      for (int j = 0; j < 8; ++j) d[j] = f2bf(xv[j]);
    }
    BARRIER_LDS();
    {
      const int tn = (tt + 1 < 64) ? t + 1 : t;   // prefetch next x
      const float* p = x + ((size_t)(bg * 16 + xrow) * T_ + tn) * F_ + xfb;
      #pragma unroll
      for (int j = 0; j < 8; ++j) xv[j] = p[j];
    }
    f32x4 acc[8];
    #pragma unroll
    for (int ct = 0; ct < 8; ++ct)
      acc[ct] = (f32x4){bias_r[ct], bias_r[ct], bias_r[ct], bias_r[ct]};
    #pragma unroll
    for (int kt = 0; kt < 4; ++kt) {
      short8 a = *(const short8*)&x_stage[bb][kt][lane][0];
      #pragma unroll
      for (int ct = 0; ct < 8; ++ct) {
        short8 b = *(const short8*)&kern_lds[(size_t)(((q * 8 + ct) * 4 + kt) * 64 + lane) * 8];
        acc[ct] = __builtin_amdgcn_mfma_f32_16x16x32_bf16(a, b, acc[ct], 0, 0, 0);
      }
    }
    uint16_t* ob = xz + ((size_t)bgm * T_ + t) * 8192;
    #pragma unroll
    for (int ct = 0; ct < 8; ++ct) {
      const uint32_t lo = (uint32_t)f2bf(acc[ct][0]) | ((uint32_t)f2bf(acc[ct][1]) << 16);
      const uint32_t hi = (uint32_t)f2bf(acc[ct][2]) | ((uint32_t)f2bf(acc[ct][3]) << 16);
      *(ull*)(ob + (size_t)((ct * 4 + q) * 64 + lane) * 4) = (ull)lo | ((ull)hi << 32);
    }
    // single barrier/iter: next iter's BAR separates this MFMA's reads from
    // the t+2 overwrite of x_stage[bb].
  }
}

// ---------------------------------------------------------------------------
// Persistent LSTM: 8 WGs x 512 thr; pair = blockIdx&3, m = blockIdx>>2.
// Each member runs FOUR chains (bg = pair*4+c) round-robin per iteration:
// each chain's agent-atomic visibility window (V ~ 5000 cyc, protocol-
// independent floor per R2/R3/R8) overlaps the other chains' compute+waits.
// acc init = precomputed xz (4 x 8B coalesced loads, 2-segment prefetch).
// All chain state statically indexed (rule #20). LDS = h_stage 64 KB only.
// ---------------------------------------------------------------------------
__global__ __launch_bounds__(512, 2) void lstm4_kernel(
    const float* __restrict__ rker, uint16_t* __restrict__ seq,
    ull* __restrict__ hbuf, const uint16_t* __restrict__ xz)
{
  const int tid  = threadIdx.x;
  const int lane = tid & 63;
  const int wv   = tid >> 6;
  const int il   = lane & 15;
  const int rg   = lane >> 4;
  const int pair = blockIdx.x & 3;
  const int m    = blockIdx.x >> 2;

  __shared__ __align__(16) uint16_t h_stage[4][2][8][64][8];   // 64 KB

  // rec B-frags in VGPR/AGPR, own-first static slots (R7 lesson):
  // kk<4: kt = m*4+kk (own half), kk>=4: peer half.
  short8 wf[4][8];
  #pragma unroll
  for (int q = 0; q < 4; ++q) {
    const int gcol = q * U_ + m * 128 + wv * 16 + il;
    #pragma unroll
    for (int kk = 0; kk < 8; ++kk) {
      const int ktg = ((kk & 4) ? (m ^ 1) : m) * 4 + (kk & 3);
      short8 v;
      #pragma unroll
      for (int j = 0; j < 8; ++j)
        v[j] = (short)f2bf(rker[(size_t)(ktg * 32 + rg * 8 + j) * G4U + gcol]);
      wf[q][kk] = v;
    }
  }

  const int u_loc = wv * 16 + il;
  const int Ua = m * 128 + u_loc;
  const int kta = Ua >> 5, ga = ((Ua & 31) >> 3) * 16, posa = Ua & 7;
  const int up_u = tid >> 2;
  const int Up = (m ^ 1) * 128 + up_u;
  const int up_kt = Up >> 5, up_g = ((Up & 31) >> 3) * 16, up_pos = Up & 7;
  const int up_rb = (tid & 3) * 4;

  ull* const pub0 = hbuf + (size_t)pair * 8192 + (size_t)m * 2048;          // +c*4096
  const ull* const peer0 = hbuf + (size_t)pair * 8192 + (size_t)(m ^ 1) * 2048;

  const uint16_t* const xzbase = xz + (size_t)(pair * 8 + m) * ((size_t)T_ * 8192);
  const size_t xzthr = (size_t)(wv * 4) * 256 + (size_t)lane * 4;   // q-step = 256 elems

  float cst[4][4];
  #pragma unroll
  for (int c = 0; c < 4; ++c)
    #pragma unroll
    for (int j = 0; j < 4; ++j) cst[c][j] = 0.f;

  // prologue: prefetch xz for chains 0,1 at t=0
  ull xzp[2][4];
  #pragma unroll
  for (int q = 0; q < 4; ++q) {
    xzp[0][q] = *(const ull*)(xzbase + (size_t)0 * 8388608 + xzthr + q * 256);
    xzp[1][q] = *(const ull*)(xzbase + (size_t)1 * 8388608 + xzthr + q * 256);
  }

  for (int t = 0; t < T_; ++t) {
    const int p_ = (t - 1) & 1;
    const uint32_t expt = (uint32_t)t;
    const ull* pl0 = peer0 + (size_t)p_ * 1024 + tid * 2;
    ull pvv[4][2];
    if (t > 0) {   // batch poll issue at iter top: V-clocks already running
      #pragma unroll
      for (int c = 0; c < 4; ++c) {
        pvv[c][0] = ald(pl0 + (size_t)c * 4096);
        pvv[c][1] = ald(pl0 + (size_t)c * 4096 + 1);
      }
    }
    #pragma unroll
    for (int c = 0; c < 4; ++c) {
      // acc <- xz(c,t) (bf16 unpack)
      f32x4 acc[4];
      #pragma unroll
      for (int q = 0; q < 4; ++q) {
        const uint32_t w0 = (uint32_t)xzp[c & 1][q];
        const uint32_t w1 = (uint32_t)(xzp[c & 1][q] >> 32);
        acc[q][0] = bf2f(w0); acc[q][1] = bf2f(w0 >> 16);
        acc[q][2] = bf2f(w1); acc[q][3] = bf2f(w1 >> 16);
      }
      // prefetch xz for chain (c+2)%4 (2 segments ahead -> HBM latency hidden)
      {
        const int cn = (c + 2) & 3;
        const int tn = (c < 2) ? t : ((t + 1 < T_) ? t + 1 : t);
        const uint16_t* pb = xzbase + (size_t)cn * 8388608 + (size_t)tn * 8192 + xzthr;
        #pragma unroll
        for (int q = 0; q < 4; ++q)
          xzp[c & 1][q] = *(const ull*)(pb + q * 256);
      }
      if (t > 0) {
        // own-half rec (h written locally last iter; barrier'd since)
        #pragma unroll
        for (int kk = 0; kk < 4; ++kk) {
          short8 a = *(const short8*)&h_stage[c][p_][m * 4 + kk][lane][0];
          #pragma unroll
          for (int q = 0; q < 4; ++q)
            acc[q] = __builtin_amdgcn_mfma_f32_16x16x32_bf16(a, wf[q][kk], acc[q], 0, 0, 0);
        }
        // wait + unpack peer half
        const ull* pp = pl0 + (size_t)c * 4096;
        while (((uint32_t)(pvv[c][0] >> 32) != expt) | ((uint32_t)(pvv[c][1] >> 32) != expt)) {
          pvv[c][0] = ald(pp); pvv[c][1] = ald(pp + 1);
        }
        const uint32_t d0 = (uint32_t)pvv[c][0], d1 = (uint32_t)pvv[c][1];
        h_stage[c][p_][up_kt][up_g + up_rb + 0][up_pos] = (uint16_t)d0;
        h_stage[c][p_][up_kt][up_g + up_rb + 1][up_pos] = (uint16_t)(d0 >> 16);
        h_stage[c][p_][up_kt][up_g + up_rb + 2][up_pos] = (uint16_t)d1;
        h_stage[c][p_][up_kt][up_g + up_rb + 3][up_pos] = (uint16_t)(d1 >> 16);
      }
      BARRIER_LDS();   // peer h_stage[c] ready (uniform at t=0 too)
      if (t > 0) {
        // peer-half rec
        #pragma unroll
        for (int kk = 0; kk < 4; ++kk) {
          short8 a = *(const short8*)&h_stage[c][p_][(m ^ 1) * 4 + kk][lane][0];
          #pragma unroll
          for (int q = 0; q < 4; ++q)
            acc[q] = __builtin_amdgcn_mfma_f32_16x16x32_bf16(a, wf[q][4 + kk], acc[q], 0, 0, 0);
        }
      }
      // gates (all in registers) + tagged publish + own-h -> LDS + seq
      uint16_t b16[4];
      #pragma unroll
      for (int j = 0; j < 4; ++j) {
        const float zi = acc[0][j], zf = acc[1][j];
        const float zg = acc[2][j], zo = acc[3][j];
        const float ii = sigm(zi), ff = sigm(zf);
        const float gg = zg * sigm(zg), oo = sigm(zo);
        const float cc = ff * cst[c][j] + ii * gg;
        cst[c][j] = cc;
        b16[j] = f2bf(oo * (cc * sigm(cc)));
      }
      {
        const int s2 = t & 1;
        ull* pw = pub0 + (size_t)c * 4096 + (size_t)s2 * 1024
                       + (size_t)u_loc * 8 + rg * 2;
        const ull tg = (ull)(uint32_t)(t + 1) << 32;
        __hip_atomic_store(pw,     (ull)((uint32_t)b16[0] | ((uint32_t)b16[1] << 16)) | tg,
                           __ATOMIC_RELAXED, __HIP_MEMORY_SCOPE_AGENT);
        __hip_atomic_store(pw + 1, (ull)((uint32_t)b16[2] | ((uint32_t)b16[3] << 16)) | tg,
                           __ATOMIC_RELAXED, __HIP_MEMORY_SCOPE_AGENT);
        #pragma unroll
        for (int j = 0; j < 4; ++j) {
          h_stage[c][s2][kta][ga + rg * 4 + j][posa] = b16[j];
          seq[((size_t)((pair * 4 + c) * 16 + rg * 4 + j) * T_ + t) * U_ + Ua] = b16[j];
        }
      }
    }
  }
}

// ---------------------------------------------------------------------------
// Fallback (ws too small for xz buffer): R8's verified pairwise kernel.
// ---------------------------------------------------------------------------
__global__ __launch_bounds__(512, 2) void lstm_fallback(
    const float* __restrict__ x, const float* __restrict__ kern,
    const float* __restrict__ rker, const float* __restrict__ bias,
    uint16_t* __restrict__ seq, ull* __restrict__ hbuf)
{
  const int tid  = threadIdx.x;
  const int lane = tid & 63;
  const int wv   = tid >> 6;
  const int il   = lane & 15;
  const int rg   = lane >> 4;
  const int bg   = blockIdx.x & 15;
  const int m    = blockIdx.x >> 4;

  __shared__ __align__(16) uint16_t x_stage[4][64][8];
  __shared__ __align__(16) uint16_t h_stage[2][8][64][8];
  __shared__ __align__(16) uint16_t kern_lds[8192 * 8];

  short8 wf[4][8];
  float  bias_r[4];
  #pragma unroll
  for (int q = 0; q < 4; ++q) {
    const int gcol = q * U_ + m * 128 + wv * 16 + il;
    bias_r[q] = bias[gcol];
    #pragma unroll
    for (int kk = 0; kk < 8; ++kk) {
      const int ktg = ((kk & 4) ? (m ^ 1) : m) * 4 + (kk & 3);
      short8 v;
      #pragma unroll
      for (int j = 0; j < 8; ++j)
        v[j] = (short)f2bf(rker[(size_t)(ktg * 32 + rg * 8 + j) * G4U + gcol]);
      wf[q][kk] = v;
    }
  }
  for (int s = 0; s < 16; ++s) {
    const int slot = tid + s * 512;
    const int ln = slot & 63, kt = (slot >> 6) & 3, ct = slot >> 8;
    const int col = (ct >> 3) * U_ + m * 128 + (ct & 7) * 16 + (ln & 15);
    const int kb  = kt * 32 + (ln >> 4) * 8;
    short8 v;
    #pragma unroll
    for (int j = 0; j < 8; ++j)
      v[j] = (short)f2bf(kern[(size_t)(kb + j) * G4U + col]);
    *(short8*)&kern_lds[(size_t)slot * 8] = v;
  }
  const int xkt = tid >> 7;
  const int xln = (tid >> 1) & 63;
  const int xj0 = (tid & 1) * 4;
  const int xrow = xln & 15;
  const int xk0  = xkt * 32 + (xln >> 4) * 8 + xj0;
  const int Ua  = m * 128 + wv * 16 + il;
  const int kta = Ua >> 5, ga = ((Ua & 31) >> 3) * 16, posa = Ua & 7;
  ull* const pub_s = hbuf + (size_t)(bg * 2 + m) * 2048;
  const ull* const pub_p = hbuf + (size_t)(bg * 2 + (m ^ 1)) * 2048;
  float cst[4];
  #pragma unroll
  for (int j = 0; j < 4; ++j) cst[j] = 0.f;
  float xp[4];
  {
    const float* p = x + ((size_t)(bg * 16 + xrow) * T_ + 0) * F_ + xk0;
    #pragma unroll
    for (int j = 0; j < 4; ++j) xp[j] = p[j];
    uint16_t* d = (uint16_t*)x_stage + tid * 4;
    #pragma unroll
    for (int j = 0; j < 4; ++j) d[j] = f2bf(xp[j]);
  }
  __syncthreads();
  for (int t = 0; t < T_; ++t) {
    const ull* pp = pub_p + (size_t)((t - 1) & 1) * 1024 + tid * 2;
    ull pv0 = 0, pv1 = 0;
    if (t > 0) {
      pv0 = ald(pp); pv1 = ald(pp + 1);
      __builtin_amdgcn_sched_barrier(0);
    }
    {
      const int tn = (t + 1 < T_) ? t + 1 : t;
      const float* p = x + ((size_t)(bg * 16 + xrow) * T_ + tn) * F_ + xk0;
      #pragma unroll
      for (int j = 0; j < 4; ++j) xp[j] = p[j];
    }
    f32x4 acc[4];
    #pragma unroll
    for (int q = 0; q < 4; ++q)
      acc[q] = (f32x4){bias_r[q], bias_r[q], bias_r[q], bias_r[q]};
    #pragma unroll
    for (int kt = 0; kt < 4; ++kt) {
      short8 a = *(const short8*)&x_stage[kt][lane][0];
      #pragma unroll
      for (int q = 0; q < 4; ++q) {
        short8 b = *(const short8*)&kern_lds[(size_t)(((q * 8 + wv) * 4 + kt) * 64 + lane) * 8];
        acc[q] = __builtin_amdgcn_mfma_f32_16x16x32_bf16(a, b, acc[q], 0, 0, 0);
      }
    }
    if (t > 0) {
      const int p_ = (t - 1) & 1;
      #pragma unroll
      for (int kk = 0; kk < 4; ++kk) {
        short8 a = *(const short8*)&h_stage[p_][m * 4 + kk][lane][0];
        #pragma unroll
        for (int q = 0; q < 4; ++q)
          acc[q] = __builtin_amdgcn_mfma_f32_16x16x32_bf16(a, wf[q][kk], acc[q], 0, 0, 0);
      }
      const uint32_t expt = (uint32_t)t;
      while (((uint32_t)(pv0 >> 32) != expt) | ((uint32_t)(pv1 >> 32) != expt)) {
        pv0 = ald(pp); pv1 = ald(pp + 1);
      }
      const int u_loc = tid >> 2;
      const int U  = (m ^ 1) * 128 + u_loc;
      const int kt = U >> 5, g = ((U & 31) >> 3) * 16, pos = U & 7;
      const int rb = (tid & 3) * 4;
      h_stage[p_][kt][g + rb + 0][pos] = (uint16_t)pv0;
      h_stage[p_][kt][g + rb + 1][pos] = (uint16_t)(pv0 >> 16);
      h_stage[p_][kt][g + rb + 2][pos] = (uint16_t)pv1;
      h_stage[p_][kt][g + rb + 3][pos] = (uint16_t)(pv1 >> 16);
    }
    BARRIER_LDS();
    if (t > 0) {
      const int p_ = (t - 1) & 1;
      #pragma unroll
      for (int kk = 0; kk < 4; ++kk) {
        short8 a = *(const short8*)&h_stage[p_][(m ^ 1) * 4 + kk][lane][0];
        #pragma unroll
        for (int q = 0; q < 4; ++q)
          acc[q] = __builtin_amdgcn_mfma_f32_16x16x32_bf16(a, wf[q][4 + kk], acc[q], 0, 0, 0);
      }
    }
    {
      uint16_t* d = (uint16_t*)x_stage + tid * 4;
      #pragma unroll
      for (int j = 0; j < 4; ++j) d[j] = f2bf(xp[j]);
    }
    {
      uint16_t b16[4];
      #pragma unroll
      for (int j = 0; j < 4; ++j) {
        const float zi = acc[0][j], zf = acc[1][j];
        const float zg = acc[2][j], zo = acc[3][j];
        const float ii = sigm(zi), ff = sigm(zf);
        const float gg = zg * sigm(zg), oo = sigm(zo);
        const float c  = ff * cst[j] + ii * gg;
        cst[j] = c;
        b16[j] = f2bf(oo * (c * sigm(c)));
      }
      const int s2 = t & 1;
      ull* pw = pub_s + (size_t)s2 * 1024 + (size_t)(wv * 16 + il) * 8 + rg * 2;
      const ull tg = (ull)(uint32_t)(t + 1) << 32;
      __hip_atomic_store(pw,     (ull)((uint32_t)b16[0] | ((uint32_t)b16[1] << 16)) | tg,
                         __ATOMIC_RELAXED, __HIP_MEMORY_SCOPE_AGENT);
      __hip_atomic_store(pw + 1, (ull)((uint32_t)b16[2] | ((uint32_t)b16[3] << 16)) | tg,
                         __ATOMIC_RELAXED, __HIP_MEMORY_SCOPE_AGENT);
      #pragma unroll
      for (int j = 0; j < 4; ++j) {
        h_stage[s2][kta][ga + rg * 4 + j][posa] = b16[j];
        seq[((size_t)(bg * 16 + rg * 4 + j) * T_ + t) * U_ + Ua] = b16[j];
      }
    }
    BARRIER_LDS();
  }
}

// ---------------------------------------------------------------------------
// Head GEMM + reduce (unchanged).
// ---------------------------------------------------------------------------
__global__ __launch_bounds__(256, 1) void head_kernel(
    const uint16_t* __restrict__ seq, const float* __restrict__ w_out,
    float* __restrict__ partials)
{
  const int g    = blockIdx.x;
  const int tid  = threadIdx.x;
  const int lane = tid & 63;
  const int wv   = tid >> 6;

  f32x4 acc[4][4];
  #pragma unroll
  for (int i = 0; i < 4; ++i)
    #pragma unroll
    for (int c = 0; c < 4; ++c) acc[i][c] = (f32x4){0.f, 0.f, 0.f, 0.f};

  for (int ks = 0; ks < 64; ++ks) {
    const int krow = g * 2048 + ks * 32 + (lane >> 4) * 8;
    short8 bf[4];
    #pragma unroll
    for (int c = 0; c < 4; ++c) {
      short8 v;
      #pragma unroll
      for (int j = 0; j < 8; ++j)
        v[j] = (short)f2bf(w_out[(size_t)(krow + j) * H_ + c * 16 + (lane & 15)]);
      bf[c] = v;
    }
    #pragma unroll
    for (int i = 0; i < 4; ++i) {
      const int b = (wv * 4 + i) * 16 + (lane & 15);
      short8 a = *(const short8*)(seq + (size_t)b * (T_ * U_) + krow);
      #pragma unroll
      for (int c = 0; c < 4; ++c)
        acc[i][c] = __builtin_amdgcn_mfma_f32_16x16x32_bf16(a, bf[c], acc[i][c], 0, 0, 0);
    }
  }
  #pragma unroll
  for (int i = 0; i < 4; ++i)
    #pragma unroll
    for (int c = 0; c < 4; ++c)
      #pragma unroll
      for (int r = 0; r < 4; ++r) {
        const int b = wv * 64 + i * 16 + (lane >> 4) * 4 + r;
        partials[((size_t)g * B_ + b) * H_ + c * 16 + (lane & 15)] = acc[i][c][r];
      }
}

__global__ void reduce_kernel(const float* __restrict__ partials,
                              const float* __restrict__ b_out,
                              float* __restrict__ out)
{
  const int i = blockIdx.x * 256 + threadIdx.x;
  float s = b_out[i & (H_ - 1)];
  #pragma unroll 8
  for (int g = 0; g < 64; ++g) s += partials[(size_t)g * (B_ * H_) + i];
  out[i] = s;
}

// ---------------------------------------------------------------------------
extern "C" void kernel_launch(void* const* d_in, const int* in_sizes, int n_in,
                              void* d_out, int out_size, void* d_ws, size_t ws_size,
                              hipStream_t stream) {
  (void)in_sizes; (void)n_in; (void)out_size;
  const float* x     = (const float*)d_in[0];
  const float* kern  = (const float*)d_in[1];
  const float* rker  = (const float*)d_in[2];
  const float* bias  = (const float*)d_in[3];
  const float* w_out = (const float*)d_in[4];
  const float* b_out = (const float*)d_in[5];
  float* out = (float*)d_out;

  char* ws = (char*)d_ws;
  const size_t seq_bytes  = (size_t)B_ * T_ * U_ * 2;    // 64 MB
  const size_t hbuf_bytes = (size_t)32 * 2048 * 8;       // 512 KB
  const size_t part_bytes = (size_t)64 * B_ * H_ * 4;    // 4 MB
  const size_t xz_bytes   = (size_t)32 * T_ * 8192 * 2;  // 256 MB bf16
  uint16_t* seq      = (uint16_t*)ws;
  ull*      hbuf     = (ull*)(ws + seq_bytes);
  float*    partials = (float*)(ws + seq_bytes + hbuf_bytes);
  uint16_t* xzbuf    = (uint16_t*)(ws + seq_bytes + hbuf_bytes + part_bytes);
  const size_t need  = seq_bytes + hbuf_bytes + part_bytes + xz_bytes;

  // per-launch re-init: stale tags from a previous graph replay would
  // false-match (tags cycle 1..512).
  hipMemsetAsync(hbuf, 0, hbuf_bytes, stream);

  if (ws_size >= need) {
    xz_pre_kernel<<<256, 256, 0, stream>>>(x, kern, bias, xzbuf);
    lstm4_kernel<<<8, 512, 0, stream>>>(rker, seq, hbuf, xzbuf);
  } else {
    lstm_fallback<<<32, 512, 0, stream>>>(x, kern, rker, bias, seq, hbuf);
  }
  head_kernel<<<64, 256, 0, stream>>>(seq, w_out, partials);
  reduce_kernel<<<64, 256, 0, stream>>>(partials, b_out, out);
}